// Round 1
// baseline (967.743 us; speedup 1.0000x reference)
//
#include <hip/hip_runtime.h>
#include <math.h>

constexpr int IN_F = 128;
constexpr int HID  = 64;
constexpr int OUT_F = 10;
constexpr int NG   = 256;
constexpr float ALPHA = 0.1f;

// ---- int32/int64 detection: int64 ids < 2^31 => every odd 32-bit word is 0 ----
__global__ void k_detect(const unsigned int* w, int nwords, int* flag) {
    __shared__ int nz;
    if (threadIdx.x == 0) nz = 0;
    __syncthreads();
    int seen = 0;
    for (int i = 1 + 2 * (int)threadIdx.x; i < nwords; i += 2 * (int)blockDim.x)
        if (w[i] != 0u) seen = 1;
    if (seen) atomicOr(&nz, 1);
    __syncthreads();
    if (threadIdx.x == 0) *flag = (nz == 0) ? 1 : 0;   // 1 => int64
}

__device__ __forceinline__ int ld_idx(const void* p, long long i, int is64) {
    return is64 ? (int)((const long long*)p)[i] : ((const int*)p)[i];
}

// ---- degree via float atomics (exact for counts < 2^24) ----
__global__ void k_deg(const void* eidx, const int* f64, int E, float* deg) {
    int e = blockIdx.x * blockDim.x + threadIdx.x;
    if (e >= E) return;
    int is64 = *f64;
    int col = ld_idx(eidx, (long long)E + e, is64);
    atomicAdd(&deg[col], 1.0f);
}

__global__ void k_dinv(float* deg, int N) {
    int i = blockIdx.x * blockDim.x + threadIdx.x;
    if (i >= N) return;
    deg[i] = rsqrtf(deg[i] + 1.0f);   // +1 self-loop; deg>=1 always
}

// ---- h = relu(x @ w1 + b1); h0 = h.  Block: 4 nodes x 64 ch ----
__global__ __launch_bounds__(256) void k_lin1(const float* __restrict__ x,
                                              const float* __restrict__ w1,
                                              const float* __restrict__ b1,
                                              float* __restrict__ h,
                                              float* __restrict__ h0, int N) {
    __shared__ float xs[4][IN_F];
    int node4 = blockIdx.x * 4;
    int ln = threadIdx.x >> 6;
    int c  = threadIdx.x & 63;
    for (int t = threadIdx.x; t < 4 * IN_F; t += 256) {
        int nn = t >> 7, kk = t & 127;
        int gn = node4 + nn;
        xs[nn][kk] = (gn < N) ? x[(long long)gn * IN_F + kk] : 0.f;
    }
    __syncthreads();
    int gn = node4 + ln;
    if (gn >= N) return;
    float acc = b1[c];
    #pragma unroll 8
    for (int k = 0; k < IN_F; ++k)
        acc = fmaf(xs[ln][k], w1[k * HID + c], acc);
    float r = fmaxf(acc, 0.f);
    h [(long long)gn * HID + c] = r;
    h0[(long long)gn * HID + c] = r;
}

// ---- agg := h * dinv^2  (self-loop term, also serves as the zero-init) ----
__global__ void k_selfloop(const float* __restrict__ h, const float* __restrict__ dinv,
                           float* __restrict__ agg, int N) {
    long long t = (long long)blockIdx.x * blockDim.x + threadIdx.x;
    if (t >= (long long)N * HID) return;
    int i = (int)(t >> 6);
    float d = dinv[i];
    agg[t] = h[t] * d * d;
}

// ---- edge scatter: agg[col] += h[row] * dinv[row]*dinv[col].  1 thread per (edge,ch) ----
__global__ __launch_bounds__(256) void k_scatter(const void* eidx, const int* f64,
                                                 const float* __restrict__ dinv,
                                                 const float* __restrict__ h,
                                                 float* agg, int E) {
    long long t = (long long)blockIdx.x * blockDim.x + threadIdx.x;
    if (t >= (long long)E * HID) return;
    int e = (int)(t >> 6);
    int c = (int)(t & 63);
    int is64 = *f64;
    int r  = ld_idx(eidx, e, is64);
    int cl = ld_idx(eidx, (long long)E + e, is64);
    float nrm = dinv[r] * dinv[cl];
    atomicAdd(&agg[(long long)cl * HID + c], h[(long long)r * HID + c] * nrm);
}

// ---- s = 0.9*agg + 0.1*h0; h = relu((1-beta)*s + beta*(s@W)) ----
__global__ __launch_bounds__(256) void k_update(const float* __restrict__ agg,
                                                const float* __restrict__ h0,
                                                const float* __restrict__ W,
                                                float beta, float* __restrict__ h, int N) {
    __shared__ float ss[4][HID];
    int node4 = blockIdx.x * 4;
    int ln = threadIdx.x >> 6;
    int c  = threadIdx.x & 63;
    int gn = node4 + ln;
    float s = 0.f;
    if (gn < N) {
        long long idx = (long long)gn * HID + c;
        s = (1.0f - ALPHA) * agg[idx] + ALPHA * h0[idx];
    }
    ss[ln][c] = s;
    __syncthreads();
    if (gn >= N) return;
    float acc = 0.f;
    #pragma unroll
    for (int k = 0; k < HID; ++k)
        acc = fmaf(ss[ln][k], W[k * HID + c], acc);
    float v = (1.f - beta) * s + beta * acc;
    h[(long long)gn * HID + c] = fmaxf(v, 0.f);
}

// ---- pooling: psum[batch[i]] += h[i]; pcnt[b] += 1 ----
__global__ __launch_bounds__(256) void k_pool(const float* __restrict__ h,
                                              const void* batch, const int* f64,
                                              float* psum, float* pcnt, int N) {
    long long t = (long long)blockIdx.x * blockDim.x + threadIdx.x;
    if (t >= (long long)N * HID) return;
    int i = (int)(t >> 6), c = (int)(t & 63);
    int b = ld_idx(batch, i, *f64);
    atomicAdd(&psum[(long long)b * HID + c], h[t]);
    if (c == 0) atomicAdd(&pcnt[b], 1.0f);
}

// ---- out[g] = (psum[g]/max(cnt,1)) @ w2 + b2 ----
__global__ void k_out(const float* __restrict__ psum, const float* __restrict__ pcnt,
                      const float* __restrict__ w2, const float* __restrict__ b2,
                      float* __restrict__ out) {
    int g = blockIdx.x;
    int tid = threadIdx.x;   // 64
    __shared__ float pr[HID];
    float cnt = fmaxf(pcnt[g], 1.0f);
    pr[tid] = psum[(long long)g * HID + tid] / cnt;
    __syncthreads();
    if (tid < OUT_F) {
        float acc = b2[tid];
        #pragma unroll
        for (int k = 0; k < HID; ++k)
            acc = fmaf(pr[k], w2[k * OUT_F + tid], acc);
        out[g * OUT_F + tid] = acc;
    }
}

static inline size_t align256(size_t x) { return (x + 255) & ~(size_t)255; }

extern "C" void kernel_launch(void* const* d_in, const int* in_sizes, int n_in,
                              void* d_out, int out_size, void* d_ws, size_t ws_size,
                              hipStream_t stream) {
    const float* x     = (const float*)d_in[0];
    const void*  eidx  = d_in[1];
    const void*  batch = d_in[2];
    const float* w1    = (const float*)d_in[3];
    const float* b1    = (const float*)d_in[4];
    const float* convw = (const float*)d_in[5];
    const float* w2    = (const float*)d_in[6];
    const float* b2    = (const float*)d_in[7];
    float* out = (float*)d_out;

    int N = in_sizes[0] / IN_F;
    int E = in_sizes[1] / 2;

    char* ws = (char*)d_ws;
    float* dinv = (float*)ws;  ws += align256((size_t)N * 4);
    float* h    = (float*)ws;  ws += align256((size_t)N * HID * 4);
    float* h0   = (float*)ws;  ws += align256((size_t)N * HID * 4);
    float* agg  = (float*)ws;  ws += align256((size_t)N * HID * 4);
    float* psum = (float*)ws;  ws += align256((size_t)NG * HID * 4);
    float* pcnt = (float*)ws;  ws += align256((size_t)NG * 4);
    int*   flag = (int*)ws;

    // 1. dtype detect (int32 vs int64 indices)
    int nwords = 4096;  // edge_index is at least 2E*4 bytes; sample prefix
    k_detect<<<1, 256, 0, stream>>>((const unsigned int*)eidx, nwords, flag);

    // 2. degrees -> dinv
    hipMemsetAsync(dinv, 0, (size_t)N * 4, stream);
    k_deg<<<(E + 255) / 256, 256, 0, stream>>>(eidx, flag, E, dinv);
    k_dinv<<<(N + 255) / 256, 256, 0, stream>>>(dinv, N);

    // 3. lin1 + relu -> h, h0
    k_lin1<<<(N + 3) / 4, 256, 0, stream>>>(x, w1, b1, h, h0, N);

    // 4. three GCN2 layers
    long long ethreads = (long long)E * HID;
    int eblocks = (int)((ethreads + 255) / 256);
    long long nthreads = (long long)N * HID;
    int nblocks = (int)((nthreads + 255) / 256);
    for (int i = 0; i < 3; ++i) {
        float beta = logf(0.5f / (float)(i + 1) + 1.0f);
        k_selfloop<<<nblocks, 256, 0, stream>>>(h, dinv, agg, N);
        k_scatter<<<eblocks, 256, 0, stream>>>(eidx, flag, dinv, h, agg, E);
        k_update<<<(N + 3) / 4, 256, 0, stream>>>(agg, h0, convw + (size_t)i * HID * HID,
                                                  beta, h, N);
    }

    // 5. pooling + final linear
    hipMemsetAsync(psum, 0, ((size_t)NG * HID + NG) * 4, stream);
    k_pool<<<nblocks, 256, 0, stream>>>(h, batch, flag, psum, pcnt, N);
    k_out<<<NG, 64, 0, stream>>>(psum, pcnt, w2, b2, out);
}

// Round 2
// 733.228 us; speedup vs baseline: 1.3198x; 1.3198x over previous
//
#include <hip/hip_runtime.h>
#include <math.h>

constexpr int IN_F = 128;
constexpr int HID  = 64;
constexpr int OUT_F = 10;
constexpr int NG   = 256;

// ---- int32/int64 detection: int64 node ids < 2^31 => every odd 32-bit word 0 ----
__global__ void k_detect(const unsigned int* w, int nwords, int* flag) {
    __shared__ int nz;
    if (threadIdx.x == 0) nz = 0;
    __syncthreads();
    int seen = 0;
    for (int i = 1 + 2 * (int)threadIdx.x; i < nwords; i += 2 * (int)blockDim.x)
        if (w[i] != 0u) seen = 1;
    if (seen) atomicOr(&nz, 1);
    __syncthreads();
    if (threadIdx.x == 0) *flag = (nz == 0) ? 1 : 0;   // 1 => int64
}

__device__ __forceinline__ int ld_idx(const void* p, long long i, int is64) {
    return is64 ? (int)((const long long*)p)[i] : ((const int*)p)[i];
}

// ---- integer in-degree histogram over targets (col) ----
__global__ void k_hist(const void* eidx, const int* f64, int E, int* degi) {
    int e = blockIdx.x * blockDim.x + threadIdx.x;
    if (e >= E) return;
    int col = ld_idx(eidx, (long long)E + e, *f64);
    atomicAdd(&degi[col], 1);
}

__global__ void k_dinv(const int* degi, float* dinv, int N) {
    int i = blockIdx.x * blockDim.x + threadIdx.x;
    if (i >= N) return;
    dinv[i] = rsqrtf((float)degi[i] + 1.0f);   // +1 self-loop
}

// ---- single-block exclusive scan of degi -> rowptr (and cursor copy) ----
__global__ __launch_bounds__(1024) void k_scan(const int* __restrict__ degi,
                                               int* rowptr, int* cursor, int N, int E) {
    __shared__ int totals[1024];
    int tid = threadIdx.x;
    int chunk = (N + 1023) / 1024;
    int start = tid * chunk;
    int end   = min(start + chunk, N);
    int s = 0;
    for (int i = start; i < end; ++i) s += degi[i];
    totals[tid] = s;
    __syncthreads();
    for (int off = 1; off < 1024; off <<= 1) {
        int add = (tid >= off) ? totals[tid - off] : 0;
        __syncthreads();
        totals[tid] += add;
        __syncthreads();
    }
    int run = totals[tid] - s;    // exclusive prefix of my chunk
    for (int i = start; i < end; ++i) {
        rowptr[i] = run; cursor[i] = run;
        run += degi[i];
    }
    if (tid == 0) rowptr[N] = E;
}

// ---- fill CSR: for edge (row -> col), append row into col's list ----
__global__ void k_fill(const void* eidx, const int* f64, int E,
                       int* cursor, int* csr_src) {
    int e = blockIdx.x * blockDim.x + threadIdx.x;
    if (e >= E) return;
    int is64 = *f64;
    int r = ld_idx(eidx, e, is64);
    int c = ld_idx(eidx, (long long)E + e, is64);
    int pos = atomicAdd(&cursor[c], 1);
    csr_src[pos] = r;
}

// ---- h = relu(x @ w1 + b1); h0 = h.  4 nodes x 64 ch per block ----
__global__ __launch_bounds__(256) void k_lin1(const float* __restrict__ x,
                                              const float* __restrict__ w1,
                                              const float* __restrict__ b1,
                                              float* __restrict__ h,
                                              float* __restrict__ h0, int N) {
    __shared__ float xs[4][IN_F];
    int node4 = blockIdx.x * 4;
    int ln = threadIdx.x >> 6;
    int c  = threadIdx.x & 63;
    for (int t = threadIdx.x; t < 4 * IN_F; t += 256) {
        int nn = t >> 7, kk = t & 127;
        int gn = node4 + nn;
        xs[nn][kk] = (gn < N) ? x[(long long)gn * IN_F + kk] : 0.f;
    }
    __syncthreads();
    int gn = node4 + ln;
    if (gn >= N) return;
    float acc = b1[c];
    #pragma unroll 8
    for (int k = 0; k < IN_F; ++k)
        acc = fmaf(xs[ln][k], w1[k * HID + c], acc);
    float r = fmaxf(acc, 0.f);
    h [(long long)gn * HID + c] = r;
    h0[(long long)gn * HID + c] = r;
}

// ---- fused GCN2 layer: gather-aggregate + residual + s@W + relu ----
// wave per node; lane c owns channel c.
__global__ __launch_bounds__(256) void k_layer(const int* __restrict__ rowptr,
                                               const int* __restrict__ csr_src,
                                               const float* __restrict__ dinv,
                                               const float* __restrict__ h_in,
                                               const float* __restrict__ h0,
                                               const float* __restrict__ W,
                                               float beta,
                                               float* __restrict__ h_out, int N) {
    __shared__ float ss[4][HID];
    int wv = threadIdx.x >> 6;
    int c  = threadIdx.x & 63;
    int node = blockIdx.x * 4 + wv;
    float s = 0.f;
    if (node < N) {
        float di = dinv[node];
        long long base = (long long)node * HID;
        float acc = di * h_in[base + c];          // self-loop (di factored out)
        int e0 = rowptr[node], e1 = rowptr[node + 1];
        for (int e = e0; e < e1; ++e) {
            int r = csr_src[e];
            acc = fmaf(h_in[(long long)r * HID + c], dinv[r], acc);
        }
        float agg = di * acc;
        s = fmaf(0.9f, agg, 0.1f * h0[base + c]); // initial residual
    }
    ss[wv][c] = s;
    __syncthreads();
    if (node >= N) return;
    float mm = 0.f;
    #pragma unroll
    for (int k = 0; k < HID; ++k)
        mm = fmaf(ss[wv][k], W[k * HID + c], mm);
    float v = s + beta * (mm - s);                // (1-b)*s + b*(s@W)
    h_out[(long long)node * HID + c] = fmaxf(v, 0.f);
}

// ---- pooling: psum[batch[i]] += h[i]; pcnt[b] += 1 ----
__global__ __launch_bounds__(256) void k_pool(const float* __restrict__ h,
                                              const void* batch, const int* f64,
                                              float* psum, float* pcnt, int N) {
    long long t = (long long)blockIdx.x * blockDim.x + threadIdx.x;
    if (t >= (long long)N * HID) return;
    int i = (int)(t >> 6), c = (int)(t & 63);
    int b = ld_idx(batch, i, *f64);
    atomicAdd(&psum[(long long)b * HID + c], h[t]);
    if (c == 0) atomicAdd(&pcnt[b], 1.0f);
}

// ---- out[g] = (psum[g]/max(cnt,1)) @ w2 + b2 ----
__global__ void k_out(const float* __restrict__ psum, const float* __restrict__ pcnt,
                      const float* __restrict__ w2, const float* __restrict__ b2,
                      float* __restrict__ out) {
    int g = blockIdx.x;
    int tid = threadIdx.x;   // 64
    __shared__ float pr[HID];
    float cnt = fmaxf(pcnt[g], 1.0f);
    pr[tid] = psum[(long long)g * HID + tid] / cnt;
    __syncthreads();
    if (tid < OUT_F) {
        float acc = b2[tid];
        #pragma unroll
        for (int k = 0; k < HID; ++k)
            acc = fmaf(pr[k], w2[k * OUT_F + tid], acc);
        out[g * OUT_F + tid] = acc;
    }
}

static inline size_t align256(size_t x) { return (x + 255) & ~(size_t)255; }

extern "C" void kernel_launch(void* const* d_in, const int* in_sizes, int n_in,
                              void* d_out, int out_size, void* d_ws, size_t ws_size,
                              hipStream_t stream) {
    const float* x     = (const float*)d_in[0];
    const void*  eidx  = d_in[1];
    const void*  batch = d_in[2];
    const float* w1    = (const float*)d_in[3];
    const float* b1    = (const float*)d_in[4];
    const float* convw = (const float*)d_in[5];
    const float* w2    = (const float*)d_in[6];
    const float* b2    = (const float*)d_in[7];
    float* out = (float*)d_out;

    int N = in_sizes[0] / IN_F;
    int E = in_sizes[1] / 2;

    char* ws = (char*)d_ws;
    float* dinv    = (float*)ws;  ws += align256((size_t)N * 4);
    float* h_a     = (float*)ws;  ws += align256((size_t)N * HID * 4);
    float* h_b     = (float*)ws;  ws += align256((size_t)N * HID * 4);
    float* h0      = (float*)ws;  ws += align256((size_t)N * HID * 4);
    float* psum    = (float*)ws;  ws += align256((size_t)NG * HID * 4);
    float* pcnt    = (float*)ws;  ws += align256((size_t)NG * 4);
    int*   degi    = (int*)ws;    ws += align256((size_t)N * 4);
    int*   rowptr  = (int*)ws;    ws += align256((size_t)(N + 1) * 4);
    int*   cursor  = (int*)ws;    ws += align256((size_t)N * 4);
    int*   csr_src = (int*)ws;    ws += align256((size_t)E * 4);
    int*   flag    = (int*)ws;

    // 1. dtype detect (int32 vs int64 indices)
    k_detect<<<1, 256, 0, stream>>>((const unsigned int*)eidx, 4096, flag);

    // 2. CSR build + dinv
    hipMemsetAsync(degi, 0, (size_t)N * 4, stream);
    k_hist<<<(E + 255) / 256, 256, 0, stream>>>(eidx, flag, E, degi);
    k_dinv<<<(N + 255) / 256, 256, 0, stream>>>(degi, dinv, N);
    k_scan<<<1, 1024, 0, stream>>>(degi, rowptr, cursor, N, E);
    k_fill<<<(E + 255) / 256, 256, 0, stream>>>(eidx, flag, E, cursor, csr_src);

    // 3. lin1 + relu -> h_a, h0
    k_lin1<<<(N + 3) / 4, 256, 0, stream>>>(x, w1, b1, h_a, h0, N);

    // 4. three fused GCN2 layers (ping-pong h_a/h_b)
    const float* hin = h_a;  float* hout = h_b;
    for (int i = 0; i < 3; ++i) {
        float beta = logf(0.5f / (float)(i + 1) + 1.0f);
        k_layer<<<(N + 3) / 4, 256, 0, stream>>>(rowptr, csr_src, dinv, hin, h0,
                                                 convw + (size_t)i * HID * HID, beta,
                                                 hout, N);
        const float* t = hin; hin = hout; hout = (float*)t;
    }

    // 5. pooling + final linear  (final h is in `hin` after the swap)
    hipMemsetAsync(psum, 0, ((size_t)NG * HID + NG) * 4, stream);
    k_pool<<<(int)(((long long)N * HID + 255) / 256), 256, 0, stream>>>(hin, batch, flag,
                                                                        psum, pcnt, N);
    k_out<<<NG, 64, 0, stream>>>(psum, pcnt, w2, b2, out);
}

// Round 3
// 446.174 us; speedup vs baseline: 2.1690x; 1.6434x over previous
//
#include <hip/hip_runtime.h>
#include <math.h>

constexpr int IN_F = 128;
constexpr int HID  = 64;
constexpr int OUT_F = 10;
constexpr int NG   = 256;

// ---- int32/int64 detection: int64 node ids < 2^31 => every odd 32-bit word 0 ----
__global__ void k_detect(const unsigned int* w, int nwords, int* flag) {
    __shared__ int nz;
    if (threadIdx.x == 0) nz = 0;
    __syncthreads();
    int seen = 0;
    for (int i = 1 + 2 * (int)threadIdx.x; i < nwords; i += 2 * (int)blockDim.x)
        if (w[i] != 0u) seen = 1;
    if (seen) atomicOr(&nz, 1);
    __syncthreads();
    if (threadIdx.x == 0) *flag = (nz == 0) ? 1 : 0;   // 1 => int64
}

__device__ __forceinline__ int ld_idx(const void* p, long long i, int is64) {
    return is64 ? (int)((const long long*)p)[i] : ((const int*)p)[i];
}

// ---- integer in-degree histogram over targets (col) ----
__global__ void k_hist(const void* eidx, const int* f64, int E, int* degi) {
    int e = blockIdx.x * blockDim.x + threadIdx.x;
    if (e >= E) return;
    int col = ld_idx(eidx, (long long)E + e, *f64);
    atomicAdd(&degi[col], 1);
}

__global__ void k_dinv(const int* degi, float* dinv, int N) {
    int i = blockIdx.x * blockDim.x + threadIdx.x;
    if (i >= N) return;
    dinv[i] = rsqrtf((float)degi[i] + 1.0f);   // +1 self-loop
}

// ---- single-block exclusive scan of degi -> rowptr (and cursor copy) ----
__global__ __launch_bounds__(1024) void k_scan(const int* __restrict__ degi,
                                               int* rowptr, int* cursor, int N, int E) {
    __shared__ int totals[1024];
    int tid = threadIdx.x;
    int chunk = (N + 1023) / 1024;
    int start = tid * chunk;
    int end   = min(start + chunk, N);
    int s = 0;
    for (int i = start; i < end; ++i) s += degi[i];
    totals[tid] = s;
    __syncthreads();
    for (int off = 1; off < 1024; off <<= 1) {
        int add = (tid >= off) ? totals[tid - off] : 0;
        __syncthreads();
        totals[tid] += add;
        __syncthreads();
    }
    int run = totals[tid] - s;    // exclusive prefix of my chunk
    for (int i = start; i < end; ++i) {
        rowptr[i] = run; cursor[i] = run;
        run += degi[i];
    }
    if (tid == 0) rowptr[N] = E;
}

// ---- fill CSR: for edge (row -> col), append row into col's list ----
__global__ void k_fill(const void* eidx, const int* f64, int E,
                       int* cursor, int* csr_src) {
    int e = blockIdx.x * blockDim.x + threadIdx.x;
    if (e >= E) return;
    int is64 = *f64;
    int r = ld_idx(eidx, e, is64);
    int c = ld_idx(eidx, (long long)E + e, is64);
    int pos = atomicAdd(&cursor[c], 1);
    csr_src[pos] = r;
}

// ---- h = relu(x @ w1 + b1); h0 = h.  4 nodes x 64 ch per block ----
__global__ __launch_bounds__(256) void k_lin1(const float* __restrict__ x,
                                              const float* __restrict__ w1,
                                              const float* __restrict__ b1,
                                              float* __restrict__ h,
                                              float* __restrict__ h0, int N) {
    __shared__ float xs[4][IN_F];
    int node4 = blockIdx.x * 4;
    int ln = threadIdx.x >> 6;
    int c  = threadIdx.x & 63;
    for (int t = threadIdx.x; t < 4 * IN_F; t += 256) {
        int nn = t >> 7, kk = t & 127;
        int gn = node4 + nn;
        xs[nn][kk] = (gn < N) ? x[(long long)gn * IN_F + kk] : 0.f;
    }
    __syncthreads();
    int gn = node4 + ln;
    if (gn >= N) return;
    float acc = b1[c];
    #pragma unroll 8
    for (int k = 0; k < IN_F; ++k)
        acc = fmaf(xs[ln][k], w1[k * HID + c], acc);
    float r = fmaxf(acc, 0.f);
    h [(long long)gn * HID + c] = r;
    h0[(long long)gn * HID + c] = r;
}

// ---- fused GCN2 layer: float4 gather (4 edges/wave-issue) + residual + s@W ----
// wave per node. lane l: quad q = l>>4 (edge slot), m = l&15 (4-channel slice).
__global__ __launch_bounds__(256) void k_layer(const int* __restrict__ rowptr,
                                               const int* __restrict__ csr_src,
                                               const float* __restrict__ dinv,
                                               const float* __restrict__ h_in,
                                               const float* __restrict__ h0,
                                               const float* __restrict__ W,
                                               float beta,
                                               float* __restrict__ h_out, int N) {
    __shared__ float ss[4][HID];
    const float4* hin4 = (const float4*)h_in;
    const float4* h04  = (const float4*)h0;
    int wv = threadIdx.x >> 6;
    int l  = threadIdx.x & 63;
    int q  = l >> 4;
    int m  = l & 15;
    int node = blockIdx.x * 4 + wv;

    if (node < N) {
        float4 acc; acc.x = acc.y = acc.z = acc.w = 0.f;
        int e0 = rowptr[node], e1 = rowptr[node + 1];
        int e = e0;
        // main: 8 edges per iteration (2 per quad), unguarded
        for (; e + 8 <= e1; e += 8) {
            int r0 = csr_src[e + q];
            int r1 = csr_src[e + 4 + q];
            float d0 = dinv[r0], d1 = dinv[r1];
            float4 v0 = hin4[(long long)r0 * 16 + m];
            float4 v1 = hin4[(long long)r1 * 16 + m];
            acc.x = fmaf(v0.x, d0, acc.x);
            acc.y = fmaf(v0.y, d0, acc.y);
            acc.z = fmaf(v0.z, d0, acc.z);
            acc.w = fmaf(v0.w, d0, acc.w);
            acc.x = fmaf(v1.x, d1, acc.x);
            acc.y = fmaf(v1.y, d1, acc.y);
            acc.z = fmaf(v1.z, d1, acc.z);
            acc.w = fmaf(v1.w, d1, acc.w);
        }
        // tail: 4 at a time, guarded per quad
        for (; e < e1; e += 4) {
            int ee = e + q;
            if (ee < e1) {
                int r = csr_src[ee];
                float d = dinv[r];
                float4 v = hin4[(long long)r * 16 + m];
                acc.x = fmaf(v.x, d, acc.x);
                acc.y = fmaf(v.y, d, acc.y);
                acc.z = fmaf(v.z, d, acc.z);
                acc.w = fmaf(v.w, d, acc.w);
            }
        }
        // fold the 4 quads: lanes l, l^16, l^32 hold partials of same channels
        #pragma unroll
        for (int off = 16; off <= 32; off <<= 1) {
            acc.x += __shfl_xor(acc.x, off, 64);
            acc.y += __shfl_xor(acc.y, off, 64);
            acc.z += __shfl_xor(acc.z, off, 64);
            acc.w += __shfl_xor(acc.w, off, 64);
        }
        // self-loop + initial residual
        float di = dinv[node];
        float4 hs  = hin4[(long long)node * 16 + m];
        float4 h0v = h04 [(long long)node * 16 + m];
        float4 s4;
        s4.x = fmaf(0.9f * di, fmaf(di, hs.x, acc.x), 0.1f * h0v.x);
        s4.y = fmaf(0.9f * di, fmaf(di, hs.y, acc.y), 0.1f * h0v.y);
        s4.z = fmaf(0.9f * di, fmaf(di, hs.z, acc.z), 0.1f * h0v.z);
        s4.w = fmaf(0.9f * di, fmaf(di, hs.w, acc.w), 0.1f * h0v.w);
        if (q == 0) *(float4*)&ss[wv][4 * m] = s4;
    }
    __syncthreads();
    if (node >= N) return;
    int c = l;
    float s = ss[wv][c];
    float mm = 0.f;
    #pragma unroll
    for (int k = 0; k < HID; ++k)
        mm = fmaf(ss[wv][k], W[k * HID + c], mm);
    float v = s + beta * (mm - s);                // (1-b)*s + b*(s@W)
    h_out[(long long)node * HID + c] = fmaxf(v, 0.f);
}

// ---- pooling: batch is SORTED -> register-accumulate, flush on boundary ----
constexpr int POOL_CHUNK = 256;   // nodes per block (64 per wave)
__global__ __launch_bounds__(256) void k_pool(const float* __restrict__ h,
                                              const void* batch, const int* f64,
                                              float* psum, float* pcnt, int N) {
    int c = threadIdx.x & 63;
    int g = threadIdx.x >> 6;          // 4 waves
    int n0 = blockIdx.x * POOL_CHUNK;
    int nend = min(n0 + POOL_CHUNK, N);
    int is64 = *f64;
    float sum = 0.f;
    int cnt = 0, curb = -1;
    for (int n = n0 + g; n < nend; n += 4) {
        int b = ld_idx(batch, n, is64);        // wave-uniform (sorted)
        if (b != curb) {
            if (curb >= 0) {
                atomicAdd(&psum[(long long)curb * HID + c], sum);
                if (c == 0) atomicAdd(&pcnt[curb], (float)cnt);
            }
            curb = b; sum = 0.f; cnt = 0;
        }
        sum += h[(long long)n * HID + c];
        cnt++;
    }
    if (curb >= 0) {
        atomicAdd(&psum[(long long)curb * HID + c], sum);
        if (c == 0) atomicAdd(&pcnt[curb], (float)cnt);
    }
}

// ---- out[g] = (psum[g]/max(cnt,1)) @ w2 + b2 ----
__global__ void k_out(const float* __restrict__ psum, const float* __restrict__ pcnt,
                      const float* __restrict__ w2, const float* __restrict__ b2,
                      float* __restrict__ out) {
    int g = blockIdx.x;
    int tid = threadIdx.x;   // 64
    __shared__ float pr[HID];
    float cnt = fmaxf(pcnt[g], 1.0f);
    pr[tid] = psum[(long long)g * HID + tid] / cnt;
    __syncthreads();
    if (tid < OUT_F) {
        float acc = b2[tid];
        #pragma unroll
        for (int k = 0; k < HID; ++k)
            acc = fmaf(pr[k], w2[k * OUT_F + tid], acc);
        out[g * OUT_F + tid] = acc;
    }
}

static inline size_t align256(size_t x) { return (x + 255) & ~(size_t)255; }

extern "C" void kernel_launch(void* const* d_in, const int* in_sizes, int n_in,
                              void* d_out, int out_size, void* d_ws, size_t ws_size,
                              hipStream_t stream) {
    const float* x     = (const float*)d_in[0];
    const void*  eidx  = d_in[1];
    const void*  batch = d_in[2];
    const float* w1    = (const float*)d_in[3];
    const float* b1    = (const float*)d_in[4];
    const float* convw = (const float*)d_in[5];
    const float* w2    = (const float*)d_in[6];
    const float* b2    = (const float*)d_in[7];
    float* out = (float*)d_out;

    int N = in_sizes[0] / IN_F;
    int E = in_sizes[1] / 2;

    char* ws = (char*)d_ws;
    float* dinv    = (float*)ws;  ws += align256((size_t)N * 4);
    float* h_a     = (float*)ws;  ws += align256((size_t)N * HID * 4);
    float* h_b     = (float*)ws;  ws += align256((size_t)N * HID * 4);
    float* h0      = (float*)ws;  ws += align256((size_t)N * HID * 4);
    float* psum    = (float*)ws;  ws += align256((size_t)NG * HID * 4);
    float* pcnt    = (float*)ws;  ws += align256((size_t)NG * 4);
    int*   degi    = (int*)ws;    ws += align256((size_t)N * 4);
    int*   rowptr  = (int*)ws;    ws += align256((size_t)(N + 1) * 4);
    int*   cursor  = (int*)ws;    ws += align256((size_t)N * 4);
    int*   csr_src = (int*)ws;    ws += align256((size_t)E * 4);
    int*   flag    = (int*)ws;

    // 1. dtype detect (int32 vs int64 indices)
    k_detect<<<1, 256, 0, stream>>>((const unsigned int*)eidx, 4096, flag);

    // 2. CSR build + dinv
    hipMemsetAsync(degi, 0, (size_t)N * 4, stream);
    k_hist<<<(E + 255) / 256, 256, 0, stream>>>(eidx, flag, E, degi);
    k_dinv<<<(N + 255) / 256, 256, 0, stream>>>(degi, dinv, N);
    k_scan<<<1, 1024, 0, stream>>>(degi, rowptr, cursor, N, E);
    k_fill<<<(E + 255) / 256, 256, 0, stream>>>(eidx, flag, E, cursor, csr_src);

    // 3. lin1 + relu -> h_a, h0
    k_lin1<<<(N + 3) / 4, 256, 0, stream>>>(x, w1, b1, h_a, h0, N);

    // 4. three fused GCN2 layers (ping-pong h_a/h_b)
    const float* hin = h_a;  float* hout = h_b;
    for (int i = 0; i < 3; ++i) {
        float beta = logf(0.5f / (float)(i + 1) + 1.0f);
        k_layer<<<(N + 3) / 4, 256, 0, stream>>>(rowptr, csr_src, dinv, hin, h0,
                                                 convw + (size_t)i * HID * HID, beta,
                                                 hout, N);
        const float* t = hin; hin = hout; hout = (float*)t;
    }

    // 5. pooling + final linear  (final h is in `hin` after the swap)
    hipMemsetAsync(psum, 0, ((size_t)NG * HID + NG) * 4, stream);
    k_pool<<<(N + POOL_CHUNK - 1) / POOL_CHUNK, 256, 0, stream>>>(hin, batch, flag,
                                                                  psum, pcnt, N);
    k_out<<<NG, 64, 0, stream>>>(psum, pcnt, w2, b2, out);
}

// Round 4
// 348.126 us; speedup vs baseline: 2.7799x; 1.2816x over previous
//
#include <hip/hip_runtime.h>
#include <math.h>

constexpr int IN_F = 128;
constexpr int HID  = 64;
constexpr int OUT_F = 10;
constexpr int NG   = 256;

// ---- int32/int64 detection: int64 node ids < 2^31 => every odd 32-bit word 0 ----
__global__ void k_detect(const unsigned int* w, int nwords, int* flag) {
    __shared__ int nz;
    if (threadIdx.x == 0) nz = 0;
    __syncthreads();
    int seen = 0;
    for (int i = 1 + 2 * (int)threadIdx.x; i < nwords; i += 2 * (int)blockDim.x)
        if (w[i] != 0u) seen = 1;
    if (seen) atomicOr(&nz, 1);
    __syncthreads();
    if (threadIdx.x == 0) *flag = (nz == 0) ? 1 : 0;   // 1 => int64
}

__device__ __forceinline__ int ld_idx(const void* p, long long i, int is64) {
    return is64 ? (int)((const long long*)p)[i] : ((const int*)p)[i];
}

// ---- integer in-degree histogram over targets (col) ----
__global__ void k_hist(const void* eidx, const int* f64, int E, int* degi) {
    int e = blockIdx.x * blockDim.x + threadIdx.x;
    if (e >= E) return;
    int col = ld_idx(eidx, (long long)E + e, *f64);
    atomicAdd(&degi[col], 1);
}

__global__ void k_dinv(const int* degi, float* dinv, int N) {
    int i = blockIdx.x * blockDim.x + threadIdx.x;
    if (i >= N) return;
    dinv[i] = rsqrtf((float)degi[i] + 1.0f);   // +1 self-loop
}

// ---- 3-phase grid-wide exclusive scan of degi -> rowptr/cursor ----
// phase 1: per-block (256 elems) reduction -> bsum[b]
__global__ __launch_bounds__(256) void k_scan1(const int* __restrict__ degi,
                                               int* __restrict__ bsum, int N) {
    __shared__ int red[256];
    int i = blockIdx.x * 256 + threadIdx.x;
    red[threadIdx.x] = (i < N) ? degi[i] : 0;
    __syncthreads();
    for (int off = 128; off > 0; off >>= 1) {
        if ((int)threadIdx.x < off) red[threadIdx.x] += red[threadIdx.x + off];
        __syncthreads();
    }
    if (threadIdx.x == 0) bsum[blockIdx.x] = red[0];
}

// phase 2: single small block exclusive-scans bsum[0..nb)
__global__ __launch_bounds__(1024) void k_scan2(int* bsum, int nb) {
    __shared__ int tot[1024];
    int tid = threadIdx.x;
    int chunk = (nb + 1023) / 1024;
    int st = tid * chunk, en = min(st + chunk, nb);
    int s = 0;
    for (int i = st; i < en; ++i) s += bsum[i];
    tot[tid] = s;
    __syncthreads();
    for (int off = 1; off < 1024; off <<= 1) {
        int add = (tid >= off) ? tot[tid - off] : 0;
        __syncthreads();
        tot[tid] += add;
        __syncthreads();
    }
    int run = tot[tid] - s;
    for (int i = st; i < en; ++i) { int v = bsum[i]; bsum[i] = run; run += v; }
}

// phase 3: per-block Hillis-Steele + block offset -> rowptr & cursor
__global__ __launch_bounds__(256) void k_scan3(const int* __restrict__ degi,
                                               const int* __restrict__ bsum,
                                               int* rowptr, int* cursor, int N, int E) {
    __shared__ int tot[256];
    int tid = threadIdx.x;
    int i = blockIdx.x * 256 + tid;
    int v = (i < N) ? degi[i] : 0;
    tot[tid] = v;
    __syncthreads();
    for (int off = 1; off < 256; off <<= 1) {
        int add = (tid >= off) ? tot[tid - off] : 0;
        __syncthreads();
        tot[tid] += add;
        __syncthreads();
    }
    if (i < N) {
        int ex = bsum[blockIdx.x] + tot[tid] - v;   // exclusive prefix
        rowptr[i] = ex; cursor[i] = ex;
    }
    if (blockIdx.x == 0 && tid == 0) rowptr[N] = E;
}

// ---- fill CSR: for edge (row -> col), append row into col's list ----
__global__ void k_fill(const void* eidx, const int* f64, int E,
                       int* cursor, int* csr_src) {
    int e = blockIdx.x * blockDim.x + threadIdx.x;
    if (e >= E) return;
    int is64 = *f64;
    int r = ld_idx(eidx, e, is64);
    int c = ld_idx(eidx, (long long)E + e, is64);
    int pos = atomicAdd(&cursor[c], 1);
    csr_src[pos] = r;
}

// ---- h = relu(x @ w1 + b1); h0 = h.  4 nodes x 64 ch per block ----
__global__ __launch_bounds__(256) void k_lin1(const float* __restrict__ x,
                                              const float* __restrict__ w1,
                                              const float* __restrict__ b1,
                                              float* __restrict__ h,
                                              float* __restrict__ h0, int N) {
    __shared__ float xs[4][IN_F];
    int node4 = blockIdx.x * 4;
    int ln = threadIdx.x >> 6;
    int c  = threadIdx.x & 63;
    for (int t = threadIdx.x; t < 4 * IN_F; t += 256) {
        int nn = t >> 7, kk = t & 127;
        int gn = node4 + nn;
        xs[nn][kk] = (gn < N) ? x[(long long)gn * IN_F + kk] : 0.f;
    }
    __syncthreads();
    int gn = node4 + ln;
    if (gn >= N) return;
    float acc = b1[c];
    #pragma unroll 8
    for (int k = 0; k < IN_F; ++k)
        acc = fmaf(xs[ln][k], w1[k * HID + c], acc);
    float r = fmaxf(acc, 0.f);
    h [(long long)gn * HID + c] = r;
    h0[(long long)gn * HID + c] = r;
}

// ---- fused GCN2 layer: float4 gather (4 edges/wave-issue) + residual + s@W ----
// wave per node. lane l: quad q = l>>4 (edge slot), m = l&15 (4-channel slice).
__global__ __launch_bounds__(256) void k_layer(const int* __restrict__ rowptr,
                                               const int* __restrict__ csr_src,
                                               const float* __restrict__ dinv,
                                               const float* __restrict__ h_in,
                                               const float* __restrict__ h0,
                                               const float* __restrict__ W,
                                               float beta,
                                               float* __restrict__ h_out, int N) {
    __shared__ float ss[4][HID];
    const float4* hin4 = (const float4*)h_in;
    const float4* h04  = (const float4*)h0;
    int wv = threadIdx.x >> 6;
    int l  = threadIdx.x & 63;
    int q  = l >> 4;
    int m  = l & 15;
    int node = blockIdx.x * 4 + wv;

    if (node < N) {
        float4 acc; acc.x = acc.y = acc.z = acc.w = 0.f;
        int e0 = rowptr[node], e1 = rowptr[node + 1];
        int e = e0;
        for (; e + 8 <= e1; e += 8) {
            int r0 = csr_src[e + q];
            int r1 = csr_src[e + 4 + q];
            float d0 = dinv[r0], d1 = dinv[r1];
            float4 v0 = hin4[(long long)r0 * 16 + m];
            float4 v1 = hin4[(long long)r1 * 16 + m];
            acc.x = fmaf(v0.x, d0, acc.x);
            acc.y = fmaf(v0.y, d0, acc.y);
            acc.z = fmaf(v0.z, d0, acc.z);
            acc.w = fmaf(v0.w, d0, acc.w);
            acc.x = fmaf(v1.x, d1, acc.x);
            acc.y = fmaf(v1.y, d1, acc.y);
            acc.z = fmaf(v1.z, d1, acc.z);
            acc.w = fmaf(v1.w, d1, acc.w);
        }
        for (; e < e1; e += 4) {
            int ee = e + q;
            if (ee < e1) {
                int r = csr_src[ee];
                float d = dinv[r];
                float4 v = hin4[(long long)r * 16 + m];
                acc.x = fmaf(v.x, d, acc.x);
                acc.y = fmaf(v.y, d, acc.y);
                acc.z = fmaf(v.z, d, acc.z);
                acc.w = fmaf(v.w, d, acc.w);
            }
        }
        #pragma unroll
        for (int off = 16; off <= 32; off <<= 1) {
            acc.x += __shfl_xor(acc.x, off, 64);
            acc.y += __shfl_xor(acc.y, off, 64);
            acc.z += __shfl_xor(acc.z, off, 64);
            acc.w += __shfl_xor(acc.w, off, 64);
        }
        float di = dinv[node];
        float4 hs  = hin4[(long long)node * 16 + m];
        float4 h0v = h04 [(long long)node * 16 + m];
        float4 s4;
        s4.x = fmaf(0.9f * di, fmaf(di, hs.x, acc.x), 0.1f * h0v.x);
        s4.y = fmaf(0.9f * di, fmaf(di, hs.y, acc.y), 0.1f * h0v.y);
        s4.z = fmaf(0.9f * di, fmaf(di, hs.z, acc.z), 0.1f * h0v.z);
        s4.w = fmaf(0.9f * di, fmaf(di, hs.w, acc.w), 0.1f * h0v.w);
        if (q == 0) *(float4*)&ss[wv][4 * m] = s4;
    }
    __syncthreads();
    if (node >= N) return;
    int c = l;
    float s = ss[wv][c];
    float mm = 0.f;
    #pragma unroll
    for (int k = 0; k < HID; ++k)
        mm = fmaf(ss[wv][k], W[k * HID + c], mm);
    float v = s + beta * (mm - s);                // (1-b)*s + b*(s@W)
    h_out[(long long)node * HID + c] = fmaxf(v, 0.f);
}

// ---- pooling: batch is SORTED -> register-accumulate, flush on boundary ----
constexpr int POOL_CHUNK = 256;   // nodes per block (64 per wave)
__global__ __launch_bounds__(256) void k_pool(const float* __restrict__ h,
                                              const void* batch, const int* f64,
                                              float* psum, float* pcnt, int N) {
    int c = threadIdx.x & 63;
    int g = threadIdx.x >> 6;          // 4 waves
    int n0 = blockIdx.x * POOL_CHUNK;
    int nend = min(n0 + POOL_CHUNK, N);
    int is64 = *f64;
    float sum = 0.f;
    int cnt = 0, curb = -1;
    for (int n = n0 + g; n < nend; n += 4) {
        int b = ld_idx(batch, n, is64);        // wave-uniform (sorted)
        if (b != curb) {
            if (curb >= 0) {
                atomicAdd(&psum[(long long)curb * HID + c], sum);
                if (c == 0) atomicAdd(&pcnt[curb], (float)cnt);
            }
            curb = b; sum = 0.f; cnt = 0;
        }
        sum += h[(long long)n * HID + c];
        cnt++;
    }
    if (curb >= 0) {
        atomicAdd(&psum[(long long)curb * HID + c], sum);
        if (c == 0) atomicAdd(&pcnt[curb], (float)cnt);
    }
}

// ---- out[g] = (psum[g]/max(cnt,1)) @ w2 + b2 ----
__global__ void k_out(const float* __restrict__ psum, const float* __restrict__ pcnt,
                      const float* __restrict__ w2, const float* __restrict__ b2,
                      float* __restrict__ out) {
    int g = blockIdx.x;
    int tid = threadIdx.x;   // 64
    __shared__ float pr[HID];
    float cnt = fmaxf(pcnt[g], 1.0f);
    pr[tid] = psum[(long long)g * HID + tid] / cnt;
    __syncthreads();
    if (tid < OUT_F) {
        float acc = b2[tid];
        #pragma unroll
        for (int k = 0; k < HID; ++k)
            acc = fmaf(pr[k], w2[k * OUT_F + tid], acc);
        out[g * OUT_F + tid] = acc;
    }
}

static inline size_t align256(size_t x) { return (x + 255) & ~(size_t)255; }

extern "C" void kernel_launch(void* const* d_in, const int* in_sizes, int n_in,
                              void* d_out, int out_size, void* d_ws, size_t ws_size,
                              hipStream_t stream) {
    const float* x     = (const float*)d_in[0];
    const void*  eidx  = d_in[1];
    const void*  batch = d_in[2];
    const float* w1    = (const float*)d_in[3];
    const float* b1    = (const float*)d_in[4];
    const float* convw = (const float*)d_in[5];
    const float* w2    = (const float*)d_in[6];
    const float* b2    = (const float*)d_in[7];
    float* out = (float*)d_out;

    int N = in_sizes[0] / IN_F;
    int E = in_sizes[1] / 2;
    int nsb = (N + 255) / 256;   // scan blocks

    char* ws = (char*)d_ws;
    float* dinv    = (float*)ws;  ws += align256((size_t)N * 4);
    float* h_a     = (float*)ws;  ws += align256((size_t)N * HID * 4);
    float* h_b     = (float*)ws;  ws += align256((size_t)N * HID * 4);
    float* h0      = (float*)ws;  ws += align256((size_t)N * HID * 4);
    float* psum    = (float*)ws;  ws += align256((size_t)NG * HID * 4);
    float* pcnt    = (float*)ws;  ws += align256((size_t)NG * 4);
    int*   degi    = (int*)ws;    ws += align256((size_t)N * 4);
    int*   rowptr  = (int*)ws;    ws += align256((size_t)(N + 1) * 4);
    int*   cursor  = (int*)ws;    ws += align256((size_t)N * 4);
    int*   csr_src = (int*)ws;    ws += align256((size_t)E * 4);
    int*   bsum    = (int*)ws;    ws += align256((size_t)nsb * 4);
    int*   flag    = (int*)ws;

    // 1. dtype detect (int32 vs int64 indices)
    k_detect<<<1, 256, 0, stream>>>((const unsigned int*)eidx, 4096, flag);

    // 2. CSR build + dinv
    hipMemsetAsync(degi, 0, (size_t)N * 4, stream);
    k_hist<<<(E + 255) / 256, 256, 0, stream>>>(eidx, flag, E, degi);
    k_dinv<<<(N + 255) / 256, 256, 0, stream>>>(degi, dinv, N);
    k_scan1<<<nsb, 256, 0, stream>>>(degi, bsum, N);
    k_scan2<<<1, 1024, 0, stream>>>(bsum, nsb);
    k_scan3<<<nsb, 256, 0, stream>>>(degi, bsum, rowptr, cursor, N, E);
    k_fill<<<(E + 255) / 256, 256, 0, stream>>>(eidx, flag, E, cursor, csr_src);

    // 3. lin1 + relu -> h_a, h0
    k_lin1<<<(N + 3) / 4, 256, 0, stream>>>(x, w1, b1, h_a, h0, N);

    // 4. three fused GCN2 layers (ping-pong h_a/h_b)
    const float* hin = h_a;  float* hout = h_b;
    for (int i = 0; i < 3; ++i) {
        float beta = logf(0.5f / (float)(i + 1) + 1.0f);
        k_layer<<<(N + 3) / 4, 256, 0, stream>>>(rowptr, csr_src, dinv, hin, h0,
                                                 convw + (size_t)i * HID * HID, beta,
                                                 hout, N);
        const float* t = hin; hin = hout; hout = (float*)t;
    }

    // 5. pooling + final linear  (final h is in `hin` after the swap)
    hipMemsetAsync(psum, 0, ((size_t)NG * HID + NG) * 4, stream);
    k_pool<<<(N + POOL_CHUNK - 1) / POOL_CHUNK, 256, 0, stream>>>(hin, batch, flag,
                                                                  psum, pcnt, N);
    k_out<<<NG, 64, 0, stream>>>(psum, pcnt, w2, b2, out);
}

// Round 5
// 303.261 us; speedup vs baseline: 3.1911x; 1.1479x over previous
//
#include <hip/hip_runtime.h>
#include <math.h>

constexpr int IN_F = 128;
constexpr int HID  = 64;
constexpr int OUT_F = 10;
constexpr int NG   = 256;

// ---- bf16 helpers (RNE) ----
__device__ __forceinline__ unsigned short f2bf(float f) {
    unsigned u = __float_as_uint(f);
    u += 0x7FFFu + ((u >> 16) & 1u);
    return (unsigned short)(u >> 16);
}
__device__ __forceinline__ float lo16(unsigned u) { return __uint_as_float(u << 16); }
__device__ __forceinline__ float hi16(unsigned u) { return __uint_as_float(u & 0xFFFF0000u); }
__device__ __forceinline__ float bf2f(unsigned short s) { return __uint_as_float((unsigned)s << 16); }

// ---- int32/int64 detection: int64 node ids < 2^31 => every odd 32-bit word 0 ----
__global__ void k_detect(const unsigned int* w, int nwords, int* flag) {
    __shared__ int nz;
    if (threadIdx.x == 0) nz = 0;
    __syncthreads();
    int seen = 0;
    for (int i = 1 + 2 * (int)threadIdx.x; i < nwords; i += 2 * (int)blockDim.x)
        if (w[i] != 0u) seen = 1;
    if (seen) atomicOr(&nz, 1);
    __syncthreads();
    if (threadIdx.x == 0) *flag = (nz == 0) ? 1 : 0;   // 1 => int64
}

__device__ __forceinline__ int ld_idx(const void* p, long long i, int is64) {
    return is64 ? (int)((const long long*)p)[i] : ((const int*)p)[i];
}

// ---- integer in-degree histogram over targets (col) ----
__global__ void k_hist(const void* eidx, const int* f64, int E, int* degi) {
    int e = blockIdx.x * blockDim.x + threadIdx.x;
    if (e >= E) return;
    int col = ld_idx(eidx, (long long)E + e, *f64);
    atomicAdd(&degi[col], 1);
}

__global__ void k_dinv(const int* degi, float* dinv, int N) {
    int i = blockIdx.x * blockDim.x + threadIdx.x;
    if (i >= N) return;
    dinv[i] = rsqrtf((float)degi[i] + 1.0f);   // +1 self-loop
}

// ---- 3-phase grid-wide exclusive scan of degi -> rowptr/cursor ----
__global__ __launch_bounds__(256) void k_scan1(const int* __restrict__ degi,
                                               int* __restrict__ bsum, int N) {
    __shared__ int red[256];
    int i = blockIdx.x * 256 + threadIdx.x;
    red[threadIdx.x] = (i < N) ? degi[i] : 0;
    __syncthreads();
    for (int off = 128; off > 0; off >>= 1) {
        if ((int)threadIdx.x < off) red[threadIdx.x] += red[threadIdx.x + off];
        __syncthreads();
    }
    if (threadIdx.x == 0) bsum[blockIdx.x] = red[0];
}

__global__ __launch_bounds__(1024) void k_scan2(int* bsum, int nb) {
    __shared__ int tot[1024];
    int tid = threadIdx.x;
    int chunk = (nb + 1023) / 1024;
    int st = tid * chunk, en = min(st + chunk, nb);
    int s = 0;
    for (int i = st; i < en; ++i) s += bsum[i];
    tot[tid] = s;
    __syncthreads();
    for (int off = 1; off < 1024; off <<= 1) {
        int add = (tid >= off) ? tot[tid - off] : 0;
        __syncthreads();
        tot[tid] += add;
        __syncthreads();
    }
    int run = tot[tid] - s;
    for (int i = st; i < en; ++i) { int v = bsum[i]; bsum[i] = run; run += v; }
}

__global__ __launch_bounds__(256) void k_scan3(const int* __restrict__ degi,
                                               const int* __restrict__ bsum,
                                               int* rowptr, int* cursor, int N, int E) {
    __shared__ int tot[256];
    int tid = threadIdx.x;
    int i = blockIdx.x * 256 + tid;
    int v = (i < N) ? degi[i] : 0;
    tot[tid] = v;
    __syncthreads();
    for (int off = 1; off < 256; off <<= 1) {
        int add = (tid >= off) ? tot[tid - off] : 0;
        __syncthreads();
        tot[tid] += add;
        __syncthreads();
    }
    if (i < N) {
        int ex = bsum[blockIdx.x] + tot[tid] - v;
        rowptr[i] = ex; cursor[i] = ex;
    }
    if (blockIdx.x == 0 && tid == 0) rowptr[N] = E;
}

// ---- fill CSR ----
__global__ void k_fill(const void* eidx, const int* f64, int E,
                       int* cursor, int* csr_src) {
    int e = blockIdx.x * blockDim.x + threadIdx.x;
    if (e >= E) return;
    int is64 = *f64;
    int r = ld_idx(eidx, e, is64);
    int c = ld_idx(eidx, (long long)E + e, is64);
    int pos = atomicAdd(&cursor[c], 1);
    csr_src[pos] = r;
}

// ---- lin1: h0 = relu(x @ w1 + b1), bf16 out.  16 nodes/block, 4 acc chains/thread ----
constexpr int NB = 16;
__global__ __launch_bounds__(256) void k_lin1(const float* __restrict__ x,
                                              const float* __restrict__ w1,
                                              const float* __restrict__ b1,
                                              unsigned short* __restrict__ h0, int N) {
    __shared__ float xs[NB][IN_F];
    int nb0 = blockIdx.x * NB;
    // stage 16 x-rows (float4, coalesced)
    for (int t = threadIdx.x; t < NB * (IN_F / 4); t += 256) {
        int n = t >> 5, k4 = t & 31;
        int gn = nb0 + n;
        float4 v = make_float4(0.f, 0.f, 0.f, 0.f);
        if (gn < N) v = ((const float4*)x)[(long long)gn * (IN_F / 4) + k4];
        *(float4*)&xs[n][k4 * 4] = v;
    }
    __syncthreads();
    int wv = threadIdx.x >> 6;
    int c  = threadIdx.x & 63;
    int n0 = wv * 4;
    float bias = b1[c];
    float a0 = bias, a1 = bias, a2 = bias, a3 = bias;
    #pragma unroll 4
    for (int k = 0; k < IN_F; k += 4) {
        float w_0 = w1[(k + 0) * HID + c];
        float w_1 = w1[(k + 1) * HID + c];
        float w_2 = w1[(k + 2) * HID + c];
        float w_3 = w1[(k + 3) * HID + c];
        float4 x0 = *(float4*)&xs[n0 + 0][k];
        float4 x1 = *(float4*)&xs[n0 + 1][k];
        float4 x2 = *(float4*)&xs[n0 + 2][k];
        float4 x3 = *(float4*)&xs[n0 + 3][k];
        a0 = fmaf(x0.x, w_0, a0); a0 = fmaf(x0.y, w_1, a0);
        a0 = fmaf(x0.z, w_2, a0); a0 = fmaf(x0.w, w_3, a0);
        a1 = fmaf(x1.x, w_0, a1); a1 = fmaf(x1.y, w_1, a1);
        a1 = fmaf(x1.z, w_2, a1); a1 = fmaf(x1.w, w_3, a1);
        a2 = fmaf(x2.x, w_0, a2); a2 = fmaf(x2.y, w_1, a2);
        a2 = fmaf(x2.z, w_2, a2); a2 = fmaf(x2.w, w_3, a2);
        a3 = fmaf(x3.x, w_0, a3); a3 = fmaf(x3.y, w_1, a3);
        a3 = fmaf(x3.z, w_2, a3); a3 = fmaf(x3.w, w_3, a3);
    }
    float acc[4] = {a0, a1, a2, a3};
    #pragma unroll
    for (int n = 0; n < 4; ++n) {
        int gn = nb0 + n0 + n;
        if (gn < N)
            h0[(long long)gn * HID + c] = f2bf(fmaxf(acc[n], 0.f));
    }
}

// ---- fused GCN2 layer, bf16 h: gather uint2 (4 edges/wave-issue) + residual + s@W ----
__global__ __launch_bounds__(256) void k_layer(const int* __restrict__ rowptr,
                                               const int* __restrict__ csr_src,
                                               const float* __restrict__ dinv,
                                               const unsigned short* __restrict__ h_in,
                                               const unsigned short* __restrict__ h0,
                                               const float* __restrict__ W,
                                               float beta,
                                               unsigned short* __restrict__ h_out, int N) {
    __shared__ float ss[4][HID];
    const uint2* hin2 = (const uint2*)h_in;   // 16 uint2 per 64-ch row
    const uint2* h02  = (const uint2*)h0;
    int wv = threadIdx.x >> 6;
    int l  = threadIdx.x & 63;
    int q  = l >> 4;
    int m  = l & 15;
    int node = blockIdx.x * 4 + wv;

    if (node < N) {
        float a0 = 0.f, a1 = 0.f, a2 = 0.f, a3 = 0.f;
        int e0 = rowptr[node], e1 = rowptr[node + 1];
        int e = e0;
        for (; e + 8 <= e1; e += 8) {
            int r0 = csr_src[e + q];
            int r1 = csr_src[e + 4 + q];
            float d0 = dinv[r0], d1 = dinv[r1];
            uint2 v0 = hin2[(long long)r0 * 16 + m];
            uint2 v1 = hin2[(long long)r1 * 16 + m];
            a0 = fmaf(lo16(v0.x), d0, a0);
            a1 = fmaf(hi16(v0.x), d0, a1);
            a2 = fmaf(lo16(v0.y), d0, a2);
            a3 = fmaf(hi16(v0.y), d0, a3);
            a0 = fmaf(lo16(v1.x), d1, a0);
            a1 = fmaf(hi16(v1.x), d1, a1);
            a2 = fmaf(lo16(v1.y), d1, a2);
            a3 = fmaf(hi16(v1.y), d1, a3);
        }
        for (; e < e1; e += 4) {
            int ee = e + q;
            if (ee < e1) {
                int r = csr_src[ee];
                float d = dinv[r];
                uint2 v = hin2[(long long)r * 16 + m];
                a0 = fmaf(lo16(v.x), d, a0);
                a1 = fmaf(hi16(v.x), d, a1);
                a2 = fmaf(lo16(v.y), d, a2);
                a3 = fmaf(hi16(v.y), d, a3);
            }
        }
        #pragma unroll
        for (int off = 16; off <= 32; off <<= 1) {
            a0 += __shfl_xor(a0, off, 64);
            a1 += __shfl_xor(a1, off, 64);
            a2 += __shfl_xor(a2, off, 64);
            a3 += __shfl_xor(a3, off, 64);
        }
        float di = dinv[node];
        uint2 hs  = hin2[(long long)node * 16 + m];
        uint2 h0v = h02 [(long long)node * 16 + m];
        float s0 = fmaf(0.9f * di, fmaf(di, lo16(hs.x), a0), 0.1f * lo16(h0v.x));
        float s1 = fmaf(0.9f * di, fmaf(di, hi16(hs.x), a1), 0.1f * hi16(h0v.x));
        float s2 = fmaf(0.9f * di, fmaf(di, lo16(hs.y), a2), 0.1f * lo16(h0v.y));
        float s3 = fmaf(0.9f * di, fmaf(di, hi16(hs.y), a3), 0.1f * hi16(h0v.y));
        if (q == 0) {
            ss[wv][4 * m + 0] = s0;
            ss[wv][4 * m + 1] = s1;
            ss[wv][4 * m + 2] = s2;
            ss[wv][4 * m + 3] = s3;
        }
    }
    __syncthreads();
    if (node >= N) return;
    int c = l;
    float s = ss[wv][c];
    float mm = 0.f;
    #pragma unroll
    for (int k = 0; k < HID; ++k)
        mm = fmaf(ss[wv][k], W[k * HID + c], mm);
    float v = s + beta * (mm - s);                // (1-b)*s + b*(s@W)
    h_out[(long long)node * HID + c] = f2bf(fmaxf(v, 0.f));
}

// ---- pooling: batch SORTED -> register-accumulate, flush on boundary ----
constexpr int POOL_CHUNK = 256;
__global__ __launch_bounds__(256) void k_pool(const unsigned short* __restrict__ h,
                                              const void* batch, const int* f64,
                                              float* psum, float* pcnt, int N) {
    int c = threadIdx.x & 63;
    int g = threadIdx.x >> 6;
    int n0 = blockIdx.x * POOL_CHUNK;
    int nend = min(n0 + POOL_CHUNK, N);
    int is64 = *f64;
    float sum = 0.f;
    int cnt = 0, curb = -1;
    for (int n = n0 + g; n < nend; n += 4) {
        int b = ld_idx(batch, n, is64);
        if (b != curb) {
            if (curb >= 0) {
                atomicAdd(&psum[(long long)curb * HID + c], sum);
                if (c == 0) atomicAdd(&pcnt[curb], (float)cnt);
            }
            curb = b; sum = 0.f; cnt = 0;
        }
        sum += bf2f(h[(long long)n * HID + c]);
        cnt++;
    }
    if (curb >= 0) {
        atomicAdd(&psum[(long long)curb * HID + c], sum);
        if (c == 0) atomicAdd(&pcnt[curb], (float)cnt);
    }
}

// ---- out[g] = (psum[g]/max(cnt,1)) @ w2 + b2 ----
__global__ void k_out(const float* __restrict__ psum, const float* __restrict__ pcnt,
                      const float* __restrict__ w2, const float* __restrict__ b2,
                      float* __restrict__ out) {
    int g = blockIdx.x;
    int tid = threadIdx.x;   // 64
    __shared__ float pr[HID];
    float cnt = fmaxf(pcnt[g], 1.0f);
    pr[tid] = psum[(long long)g * HID + tid] / cnt;
    __syncthreads();
    if (tid < OUT_F) {
        float acc = b2[tid];
        #pragma unroll
        for (int k = 0; k < HID; ++k)
            acc = fmaf(pr[k], w2[k * OUT_F + tid], acc);
        out[g * OUT_F + tid] = acc;
    }
}

static inline size_t align256(size_t x) { return (x + 255) & ~(size_t)255; }

extern "C" void kernel_launch(void* const* d_in, const int* in_sizes, int n_in,
                              void* d_out, int out_size, void* d_ws, size_t ws_size,
                              hipStream_t stream) {
    const float* x     = (const float*)d_in[0];
    const void*  eidx  = d_in[1];
    const void*  batch = d_in[2];
    const float* w1    = (const float*)d_in[3];
    const float* b1    = (const float*)d_in[4];
    const float* convw = (const float*)d_in[5];
    const float* w2    = (const float*)d_in[6];
    const float* b2    = (const float*)d_in[7];
    float* out = (float*)d_out;

    int N = in_sizes[0] / IN_F;
    int E = in_sizes[1] / 2;
    int nsb = (N + 255) / 256;

    char* ws = (char*)d_ws;
    float* dinv    = (float*)ws;            ws += align256((size_t)N * 4);
    unsigned short* h0  = (unsigned short*)ws;  ws += align256((size_t)N * HID * 2);
    unsigned short* h_b = (unsigned short*)ws;  ws += align256((size_t)N * HID * 2);
    unsigned short* h_c = (unsigned short*)ws;  ws += align256((size_t)N * HID * 2);
    float* psum    = (float*)ws;            ws += align256((size_t)NG * HID * 4);
    float* pcnt    = (float*)ws;            ws += align256((size_t)NG * 4);
    int*   degi    = (int*)ws;              ws += align256((size_t)N * 4);
    int*   rowptr  = (int*)ws;              ws += align256((size_t)(N + 1) * 4);
    int*   cursor  = (int*)ws;              ws += align256((size_t)N * 4);
    int*   csr_src = (int*)ws;              ws += align256((size_t)E * 4);
    int*   bsum    = (int*)ws;              ws += align256((size_t)nsb * 4);
    int*   flag    = (int*)ws;

    // 1. dtype detect
    k_detect<<<1, 256, 0, stream>>>((const unsigned int*)eidx, 4096, flag);

    // 2. CSR build + dinv
    hipMemsetAsync(degi, 0, (size_t)N * 4, stream);
    k_hist<<<(E + 255) / 256, 256, 0, stream>>>(eidx, flag, E, degi);
    k_dinv<<<(N + 255) / 256, 256, 0, stream>>>(degi, dinv, N);
    k_scan1<<<nsb, 256, 0, stream>>>(degi, bsum, N);
    k_scan2<<<1, 1024, 0, stream>>>(bsum, nsb);
    k_scan3<<<nsb, 256, 0, stream>>>(degi, bsum, rowptr, cursor, N, E);
    k_fill<<<(E + 255) / 256, 256, 0, stream>>>(eidx, flag, E, cursor, csr_src);

    // 3. lin1 + relu -> h0 (bf16; also serves as layer-1 input)
    k_lin1<<<(N + NB - 1) / NB, 256, 0, stream>>>(x, w1, b1, h0, N);

    // 4. three fused GCN2 layers: h0->h_b->h_c->h_b
    const unsigned short* hin = h0;
    unsigned short* houts[3] = {h_b, h_c, h_b};
    for (int i = 0; i < 3; ++i) {
        float beta = logf(0.5f / (float)(i + 1) + 1.0f);
        k_layer<<<(N + 3) / 4, 256, 0, stream>>>(rowptr, csr_src, dinv, hin, h0,
                                                 convw + (size_t)i * HID * HID, beta,
                                                 houts[i], N);
        hin = houts[i];
    }

    // 5. pooling + final linear (final h is h_b)
    hipMemsetAsync(psum, 0, ((size_t)NG * HID + NG) * 4, stream);
    k_pool<<<(N + POOL_CHUNK - 1) / POOL_CHUNK, 256, 0, stream>>>(h_b, batch, flag,
                                                                  psum, pcnt, N);
    k_out<<<NG, 64, 0, stream>>>(psum, pcnt, w2, b2, out);
}

// Round 6
// 290.094 us; speedup vs baseline: 3.3360x; 1.0454x over previous
//
#include <hip/hip_runtime.h>
#include <math.h>

constexpr int IN_F = 128;
constexpr int HID  = 64;
constexpr int OUT_F = 10;
constexpr int NG   = 256;

// ---- bf16 helpers (RNE) ----
__device__ __forceinline__ unsigned short f2bf(float f) {
    unsigned u = __float_as_uint(f);
    u += 0x7FFFu + ((u >> 16) & 1u);
    return (unsigned short)(u >> 16);
}
__device__ __forceinline__ float lo16(unsigned u) { return __uint_as_float(u << 16); }
__device__ __forceinline__ float hi16(unsigned u) { return __uint_as_float(u & 0xFFFF0000u); }
__device__ __forceinline__ float bf2f(unsigned short s) { return __uint_as_float((unsigned)s << 16); }

// accumulate 8 bf16 (one uint4) into a[0..7]
__device__ __forceinline__ void acc8(float* a, uint4 v) {
    a[0] += lo16(v.x); a[1] += hi16(v.x);
    a[2] += lo16(v.y); a[3] += hi16(v.y);
    a[4] += lo16(v.z); a[5] += hi16(v.z);
    a[6] += lo16(v.w); a[7] += hi16(v.w);
}

// ---- int32/int64 detection ----
__global__ void k_detect(const unsigned int* w, int nwords, int* flag) {
    __shared__ int nz;
    if (threadIdx.x == 0) nz = 0;
    __syncthreads();
    int seen = 0;
    for (int i = 1 + 2 * (int)threadIdx.x; i < nwords; i += 2 * (int)blockDim.x)
        if (w[i] != 0u) seen = 1;
    if (seen) atomicOr(&nz, 1);
    __syncthreads();
    if (threadIdx.x == 0) *flag = (nz == 0) ? 1 : 0;   // 1 => int64
}

__device__ __forceinline__ int ld_idx(const void* p, long long i, int is64) {
    return is64 ? (int)((const long long*)p)[i] : ((const int*)p)[i];
}

// ---- in-degree histogram over targets ----
__global__ void k_hist(const void* eidx, const int* f64, int E, int* degi) {
    int e = blockIdx.x * blockDim.x + threadIdx.x;
    if (e >= E) return;
    int col = ld_idx(eidx, (long long)E + e, *f64);
    atomicAdd(&degi[col], 1);
}

__global__ void k_dinv(const int* degi, float* dinv, int N) {
    int i = blockIdx.x * blockDim.x + threadIdx.x;
    if (i >= N) return;
    dinv[i] = rsqrtf((float)degi[i] + 1.0f);
}

// ---- 3-phase grid-wide exclusive scan ----
__global__ __launch_bounds__(256) void k_scan1(const int* __restrict__ degi,
                                               int* __restrict__ bsum, int N) {
    __shared__ int red[256];
    int i = blockIdx.x * 256 + threadIdx.x;
    red[threadIdx.x] = (i < N) ? degi[i] : 0;
    __syncthreads();
    for (int off = 128; off > 0; off >>= 1) {
        if ((int)threadIdx.x < off) red[threadIdx.x] += red[threadIdx.x + off];
        __syncthreads();
    }
    if (threadIdx.x == 0) bsum[blockIdx.x] = red[0];
}

__global__ __launch_bounds__(1024) void k_scan2(int* bsum, int nb) {
    __shared__ int tot[1024];
    int tid = threadIdx.x;
    int chunk = (nb + 1023) / 1024;
    int st = tid * chunk, en = min(st + chunk, nb);
    int s = 0;
    for (int i = st; i < en; ++i) s += bsum[i];
    tot[tid] = s;
    __syncthreads();
    for (int off = 1; off < 1024; off <<= 1) {
        int add = (tid >= off) ? tot[tid - off] : 0;
        __syncthreads();
        tot[tid] += add;
        __syncthreads();
    }
    int run = tot[tid] - s;
    for (int i = st; i < en; ++i) { int v = bsum[i]; bsum[i] = run; run += v; }
}

__global__ __launch_bounds__(256) void k_scan3(const int* __restrict__ degi,
                                               const int* __restrict__ bsum,
                                               int* rowptr, int* cursor, int N, int E) {
    __shared__ int tot[256];
    int tid = threadIdx.x;
    int i = blockIdx.x * 256 + tid;
    int v = (i < N) ? degi[i] : 0;
    tot[tid] = v;
    __syncthreads();
    for (int off = 1; off < 256; off <<= 1) {
        int add = (tid >= off) ? tot[tid - off] : 0;
        __syncthreads();
        tot[tid] += add;
        __syncthreads();
    }
    if (i < N) {
        int ex = bsum[blockIdx.x] + tot[tid] - v;
        rowptr[i] = ex; cursor[i] = ex;
    }
    if (blockIdx.x == 0 && tid == 0) rowptr[N] = E;
}

// ---- fill CSR ----
__global__ void k_fill(const void* eidx, const int* f64, int E,
                       int* cursor, int* csr_src) {
    int e = blockIdx.x * blockDim.x + threadIdx.x;
    if (e >= E) return;
    int is64 = *f64;
    int r = ld_idx(eidx, e, is64);
    int c = ld_idx(eidx, (long long)E + e, is64);
    int pos = atomicAdd(&cursor[c], 1);
    csr_src[pos] = r;
}

// ---- lin1: h0 = relu(x@w1+b1) raw bf16; hs0 = h0*dinv bf16 ----
constexpr int NB = 16;
__global__ __launch_bounds__(256) void k_lin1(const float* __restrict__ x,
                                              const float* __restrict__ w1,
                                              const float* __restrict__ b1,
                                              const float* __restrict__ dinv,
                                              unsigned short* __restrict__ h0,
                                              unsigned short* __restrict__ hs0, int N) {
    __shared__ float xs[NB][IN_F];
    int nb0 = blockIdx.x * NB;
    for (int t = threadIdx.x; t < NB * (IN_F / 4); t += 256) {
        int n = t >> 5, k4 = t & 31;
        int gn = nb0 + n;
        float4 v = make_float4(0.f, 0.f, 0.f, 0.f);
        if (gn < N) v = ((const float4*)x)[(long long)gn * (IN_F / 4) + k4];
        *(float4*)&xs[n][k4 * 4] = v;
    }
    __syncthreads();
    int wv = threadIdx.x >> 6;
    int c  = threadIdx.x & 63;
    int n0 = wv * 4;
    float bias = b1[c];
    float a0 = bias, a1 = bias, a2 = bias, a3 = bias;
    #pragma unroll 4
    for (int k = 0; k < IN_F; k += 4) {
        float w_0 = w1[(k + 0) * HID + c];
        float w_1 = w1[(k + 1) * HID + c];
        float w_2 = w1[(k + 2) * HID + c];
        float w_3 = w1[(k + 3) * HID + c];
        float4 x0 = *(float4*)&xs[n0 + 0][k];
        float4 x1 = *(float4*)&xs[n0 + 1][k];
        float4 x2 = *(float4*)&xs[n0 + 2][k];
        float4 x3 = *(float4*)&xs[n0 + 3][k];
        a0 = fmaf(x0.x, w_0, a0); a0 = fmaf(x0.y, w_1, a0);
        a0 = fmaf(x0.z, w_2, a0); a0 = fmaf(x0.w, w_3, a0);
        a1 = fmaf(x1.x, w_0, a1); a1 = fmaf(x1.y, w_1, a1);
        a1 = fmaf(x1.z, w_2, a1); a1 = fmaf(x1.w, w_3, a1);
        a2 = fmaf(x2.x, w_0, a2); a2 = fmaf(x2.y, w_1, a2);
        a2 = fmaf(x2.z, w_2, a2); a2 = fmaf(x2.w, w_3, a2);
        a3 = fmaf(x3.x, w_0, a3); a3 = fmaf(x3.y, w_1, a3);
        a3 = fmaf(x3.z, w_2, a3); a3 = fmaf(x3.w, w_3, a3);
    }
    float acc[4] = {a0, a1, a2, a3};
    #pragma unroll
    for (int n = 0; n < 4; ++n) {
        int gn = nb0 + n0 + n;
        if (gn < N) {
            float r = fmaxf(acc[n], 0.f);
            h0 [(long long)gn * HID + c] = f2bf(r);
            hs0[(long long)gn * HID + c] = f2bf(r * dinv[gn]);
        }
    }
}

// ---- fused GCN2 layer, pre-scaled bf16 hs: pure-add gather (uint4, 16 edges in
// flight) + residual + s@W.  lane l: edge slot q=l>>3, channel octet m=l&7. ----
__global__ __launch_bounds__(256) void k_layer(const int* __restrict__ rowptr,
                                               const int* __restrict__ csr_src,
                                               const float* __restrict__ dinv,
                                               const unsigned short* __restrict__ hs_in,
                                               const unsigned short* __restrict__ h0,
                                               const float* __restrict__ W,
                                               float beta, int scale_out,
                                               unsigned short* __restrict__ h_out, int N) {
    __shared__ float ss[4][HID];
    const uint4* hin4 = (const uint4*)hs_in;   // 8 uint4 per 64-ch bf16 row
    const uint4* h04  = (const uint4*)h0;
    int wv = threadIdx.x >> 6;
    int l  = threadIdx.x & 63;
    int q  = l >> 3;
    int m  = l & 7;
    int node = blockIdx.x * 4 + wv;

    if (node < N) {
        float a[8] = {0.f, 0.f, 0.f, 0.f, 0.f, 0.f, 0.f, 0.f};
        int e0 = rowptr[node], e1 = rowptr[node + 1];
        int e = e0;
        for (; e + 16 <= e1; e += 16) {
            int r0 = csr_src[e + q];
            int r1 = csr_src[e + 8 + q];
            uint4 v0 = hin4[(long long)r0 * 8 + m];
            uint4 v1 = hin4[(long long)r1 * 8 + m];
            acc8(a, v0);
            acc8(a, v1);
        }
        if (e < e1) {
            int ee0 = e + q, ee1 = e + 8 + q;
            if (ee0 < e1) {
                int r = csr_src[ee0];
                uint4 v = hin4[(long long)r * 8 + m];
                acc8(a, v);
            }
            if (ee1 < e1) {
                int r = csr_src[ee1];
                uint4 v = hin4[(long long)r * 8 + m];
                acc8(a, v);
            }
        }
        // fold 8 edge slots: lanes differing in bits 3..5 hold same channels
        #pragma unroll
        for (int off = 8; off <= 32; off <<= 1) {
            #pragma unroll
            for (int j = 0; j < 8; ++j) a[j] += __shfl_xor(a[j], off, 64);
        }
        if (q == 0) {   // lanes 0..7: m = l, own channels 8m..8m+7
            float di = dinv[node];
            uint4 hv = hin4[(long long)node * 8 + m];
            uint4 rv = h04 [(long long)node * 8 + m];
            float hs[8] = {lo16(hv.x), hi16(hv.x), lo16(hv.y), hi16(hv.y),
                           lo16(hv.z), hi16(hv.z), lo16(hv.w), hi16(hv.w)};
            float r0[8] = {lo16(rv.x), hi16(rv.x), lo16(rv.y), hi16(rv.y),
                           lo16(rv.z), hi16(rv.z), lo16(rv.w), hi16(rv.w)};
            float s[8];
            #pragma unroll
            for (int j = 0; j < 8; ++j)
                s[j] = fmaf(0.9f * di, a[j] + hs[j], 0.1f * r0[j]);
            *(float4*)&ss[wv][8 * m]     = make_float4(s[0], s[1], s[2], s[3]);
            *(float4*)&ss[wv][8 * m + 4] = make_float4(s[4], s[5], s[6], s[7]);
        }
    }
    __syncthreads();
    if (node >= N) return;
    int c = l;
    float s = ss[wv][c];
    float mm = 0.f;
    const float4* ssv = (const float4*)&ss[wv][0];
    #pragma unroll
    for (int k4 = 0; k4 < 16; ++k4) {
        float4 sv = ssv[k4];
        mm = fmaf(sv.x, W[(4 * k4 + 0) * HID + c], mm);
        mm = fmaf(sv.y, W[(4 * k4 + 1) * HID + c], mm);
        mm = fmaf(sv.z, W[(4 * k4 + 2) * HID + c], mm);
        mm = fmaf(sv.w, W[(4 * k4 + 3) * HID + c], mm);
    }
    float v = fmaxf(s + beta * (mm - s), 0.f);
    if (scale_out) v *= dinv[node];      // pre-scale for next layer's gather
    h_out[(long long)node * HID + c] = f2bf(v);
}

// ---- pooling: batch SORTED -> register-accumulate, flush on boundary ----
constexpr int POOL_CHUNK = 256;
__global__ __launch_bounds__(256) void k_pool(const unsigned short* __restrict__ h,
                                              const void* batch, const int* f64,
                                              float* psum, float* pcnt, int N) {
    int c = threadIdx.x & 63;
    int g = threadIdx.x >> 6;
    int n0 = blockIdx.x * POOL_CHUNK;
    int nend = min(n0 + POOL_CHUNK, N);
    int is64 = *f64;
    float sum = 0.f;
    int cnt = 0, curb = -1;
    for (int n = n0 + g; n < nend; n += 4) {
        int b = ld_idx(batch, n, is64);
        if (b != curb) {
            if (curb >= 0) {
                atomicAdd(&psum[(long long)curb * HID + c], sum);
                if (c == 0) atomicAdd(&pcnt[curb], (float)cnt);
            }
            curb = b; sum = 0.f; cnt = 0;
        }
        sum += bf2f(h[(long long)n * HID + c]);
        cnt++;
    }
    if (curb >= 0) {
        atomicAdd(&psum[(long long)curb * HID + c], sum);
        if (c == 0) atomicAdd(&pcnt[curb], (float)cnt);
    }
}

// ---- out[g] = (psum[g]/max(cnt,1)) @ w2 + b2 ----
__global__ void k_out(const float* __restrict__ psum, const float* __restrict__ pcnt,
                      const float* __restrict__ w2, const float* __restrict__ b2,
                      float* __restrict__ out) {
    int g = blockIdx.x;
    int tid = threadIdx.x;   // 64
    __shared__ float pr[HID];
    float cnt = fmaxf(pcnt[g], 1.0f);
    pr[tid] = psum[(long long)g * HID + tid] / cnt;
    __syncthreads();
    if (tid < OUT_F) {
        float acc = b2[tid];
        #pragma unroll
        for (int k = 0; k < HID; ++k)
            acc = fmaf(pr[k], w2[k * OUT_F + tid], acc);
        out[g * OUT_F + tid] = acc;
    }
}

static inline size_t align256(size_t x) { return (x + 255) & ~(size_t)255; }

extern "C" void kernel_launch(void* const* d_in, const int* in_sizes, int n_in,
                              void* d_out, int out_size, void* d_ws, size_t ws_size,
                              hipStream_t stream) {
    const float* x     = (const float*)d_in[0];
    const void*  eidx  = d_in[1];
    const void*  batch = d_in[2];
    const float* w1    = (const float*)d_in[3];
    const float* b1    = (const float*)d_in[4];
    const float* convw = (const float*)d_in[5];
    const float* w2    = (const float*)d_in[6];
    const float* b2    = (const float*)d_in[7];
    float* out = (float*)d_out;

    int N = in_sizes[0] / IN_F;
    int E = in_sizes[1] / 2;
    int nsb = (N + 255) / 256;

    char* ws = (char*)d_ws;
    float* dinv    = (float*)ws;            ws += align256((size_t)N * 4);
    unsigned short* h0  = (unsigned short*)ws;  ws += align256((size_t)N * HID * 2);
    unsigned short* hs0 = (unsigned short*)ws;  ws += align256((size_t)N * HID * 2);
    unsigned short* hb  = (unsigned short*)ws;  ws += align256((size_t)N * HID * 2);
    unsigned short* hc  = (unsigned short*)ws;  ws += align256((size_t)N * HID * 2);
    float* psum    = (float*)ws;            ws += align256((size_t)NG * HID * 4);
    float* pcnt    = (float*)ws;            ws += align256((size_t)NG * 4);
    int*   degi    = (int*)ws;              ws += align256((size_t)N * 4);
    int*   rowptr  = (int*)ws;              ws += align256((size_t)(N + 1) * 4);
    int*   cursor  = (int*)ws;              ws += align256((size_t)N * 4);
    int*   csr_src = (int*)ws;              ws += align256((size_t)E * 4);
    int*   bsum    = (int*)ws;              ws += align256((size_t)nsb * 4);
    int*   flag    = (int*)ws;

    // 1. dtype detect
    k_detect<<<1, 256, 0, stream>>>((const unsigned int*)eidx, 4096, flag);

    // 2. CSR build + dinv
    hipMemsetAsync(degi, 0, (size_t)N * 4, stream);
    k_hist<<<(E + 255) / 256, 256, 0, stream>>>(eidx, flag, E, degi);
    k_dinv<<<(N + 255) / 256, 256, 0, stream>>>(degi, dinv, N);
    k_scan1<<<nsb, 256, 0, stream>>>(degi, bsum, N);
    k_scan2<<<1, 1024, 0, stream>>>(bsum, nsb);
    k_scan3<<<nsb, 256, 0, stream>>>(degi, bsum, rowptr, cursor, N, E);
    k_fill<<<(E + 255) / 256, 256, 0, stream>>>(eidx, flag, E, cursor, csr_src);

    // 3. lin1 -> h0 (raw) + hs0 (scaled)
    k_lin1<<<(N + NB - 1) / NB, 256, 0, stream>>>(x, w1, b1, dinv, h0, hs0, N);

    // 4. three fused GCN2 layers: hs0 -> hb -> hc -> hb(raw)
    int nlb = (N + 3) / 4;
    float beta0 = logf(0.5f / 1.0f + 1.0f);
    float beta1 = logf(0.5f / 2.0f + 1.0f);
    float beta2 = logf(0.5f / 3.0f + 1.0f);
    k_layer<<<nlb, 256, 0, stream>>>(rowptr, csr_src, dinv, hs0, h0,
                                     convw + 0 * HID * HID, beta0, 1, hb, N);
    k_layer<<<nlb, 256, 0, stream>>>(rowptr, csr_src, dinv, hb, h0,
                                     convw + 1 * HID * HID, beta1, 1, hc, N);
    k_layer<<<nlb, 256, 0, stream>>>(rowptr, csr_src, dinv, hc, h0,
                                     convw + 2 * HID * HID, beta2, 0, hb, N);

    // 5. pooling + final linear (raw h is hb)
    hipMemsetAsync(psum, 0, ((size_t)NG * HID + NG) * 4, stream);
    k_pool<<<(N + POOL_CHUNK - 1) / POOL_CHUNK, 256, 0, stream>>>(hb, batch, flag,
                                                                  psum, pcnt, N);
    k_out<<<NG, 64, 0, stream>>>(psum, pcnt, w2, b2, out);
}